// Round 8
// baseline (273.522 us; speedup 1.0000x reference)
//
#include <hip/hip_runtime.h>
#include <hip/hip_bf16.h>
#include <math.h>

// ---------------------------------------------------------------------------
// CrossModalAttention on MI355X (gfx950)
//   B=4, Cu=320, Cj=1024, H=W=64 (N=4096), ATTN_DIM=256, scale = 1/16
// Round 7: attn inner loop software-pipelined (T15): body i = QK(i+1) [MFMA]
// + softmax(i) [VALU, interleaved by compiler] + PV(i). ONE barrier per tile
// (vmcnt(0) of own stage at body end + barrier at body top). Carried score
// register (16 VGPR), single QK accumulator. Everything else from R6.
// ---------------------------------------------------------------------------

typedef unsigned short u16;
typedef __attribute__((ext_vector_type(8))) short bf16x8;
typedef __attribute__((ext_vector_type(4))) float f32x4;
typedef __attribute__((ext_vector_type(16))) float f32x16;
typedef __attribute__((ext_vector_type(4))) unsigned short u16x4;

#define NB 4
#define CU 320
#define CJ 1024
#define NN 4096
#define AD 256

// ws layout (bytes)
#define XU_OFF 0u
#define XJ_OFF 10485760u
#define QB_OFF 44040192u
#define KB_OFF 52428800u
#define VB_OFF 60817408u
#define WQ_OFF 71303168u
#define WK_OFF 71467008u
#define WV_OFF 71991296u
#define WO_OFF 72646656u
#define AO_OFF XU_OFF

__device__ __forceinline__ u16 f2b(float f) {
    union { float f; unsigned u; } v; v.f = f;
    unsigned u = v.u;
    unsigned r = (u + 0x7fffu + ((u >> 16) & 1u)) >> 16;
    return (u16)r;
}

__device__ __forceinline__ unsigned cvt_pk_bf16(float lo, float hi) {
    unsigned r;
    asm("v_cvt_pk_bf16_f32 %0, %1, %2" : "=v"(r) : "v"(lo), "v"(hi));
    return r;
}

__device__ __forceinline__ float exp2_fast(float x) {
    float r;
    asm("v_exp_f32 %0, %1" : "=v"(r) : "v"(x));
    return r;
}

__device__ __forceinline__ void async_cp16(const u16* g, char* l) {
    __builtin_amdgcn_global_load_lds(
        (const __attribute__((address_space(1))) unsigned int*)g,
        (__attribute__((address_space(3))) unsigned int*)l, 16, 0, 0);
}

// ---------------- weight cast ----------------
__global__ void wcast_kernel(const float* __restrict__ Wq, const float* __restrict__ Wk,
                             const float* __restrict__ Wv, const float* __restrict__ Wo,
                             u16* __restrict__ wq, u16* __restrict__ wk,
                             u16* __restrict__ wv, u16* __restrict__ wo) {
    int id = blockIdx.x * 256 + threadIdx.x;
    if (id < 81920) { wq[id] = f2b(Wq[id]); return; }
    id -= 81920;
    if (id < 262144) { wk[id] = f2b(Wk[id]); return; }
    id -= 262144;
    if (id < 327680) { wv[id] = f2b(Wv[id]); return; }
    id -= 327680;
    if (id < 102400) { wo[id] = f2b(Wo[id]); }
}

// ---------------- transpose [C][N] f32 -> [N][C] bf16 ----------------
__global__ __launch_bounds__(256) void transpose_cast_kernel(
        const float* __restrict__ in, u16* __restrict__ out, int C, int Nn) {
    __shared__ float tile[64][65];
    int b = blockIdx.z;
    int n0 = blockIdx.x * 64, c0 = blockIdx.y * 64;
    const float* src = in + (size_t)b * C * Nn;
    u16* dst = out + (size_t)b * Nn * C;
    int t = threadIdx.x;
    int nl = t & 63, cl = t >> 6;
    #pragma unroll
    for (int k = 0; k < 16; ++k) {
        int c = cl + k * 4;
        tile[c][nl] = src[(size_t)(c0 + c) * Nn + n0 + nl];
    }
    __syncthreads();
    int cl2 = t & 63, nl2 = t >> 6;
    #pragma unroll
    for (int k = 0; k < 16; ++k) {
        int n = nl2 + k * 4;
        dst[(size_t)(n0 + n) * C + c0 + cl2] = f2b(tile[cl2][n]);
    }
}

// ---------------- unified GEMM: out = A(16384xKD) @ W(NOUTxKD)^T ----------------
template <int EPI, int KD, int NOUT>
__global__ __launch_bounds__(256, 2) void gemm_kernel(
        const u16* __restrict__ A, const u16* __restrict__ W,
        const float* __restrict__ bias, void* __restrict__ outp,
        const float* __restrict__ unet, float alpha) {
    __shared__ __align__(16) char smem[49152];
    const int t = threadIdx.x;
    const int lane = t & 63, wave = t >> 6;
    const int r = lane & 15, h = lane >> 4;
    const int wr = wave >> 1, wc = wave & 1;
    const int m0 = blockIdx.x * 128;
    const int bn0 = blockIdx.y * 64;

    int goffA[4], goffB[2];
    #pragma unroll
    for (int n = 0; n < 4; ++n) {
        int c = n * 256 + t;
        int row = c >> 3, s = c & 7;
        goffA[n] = (m0 + row) * KD + ((s ^ (row & 7)) << 3);
    }
    #pragma unroll
    for (int n = 0; n < 2; ++n) {
        int c = n * 256 + t;
        int row = c >> 3, s = c & 7;
        goffB[n] = (bn0 + row) * KD + ((s ^ (row & 7)) << 3);
    }
    const unsigned wb = (unsigned)(t & ~63) * 16u;

    #define GSTAGE(BUF, KT) do {                                                  \
        _Pragma("unroll")                                                         \
        for (int n_ = 0; n_ < 4; ++n_)                                            \
            async_cp16(A + goffA[n_] + (KT) * 64,                                 \
                       smem + (BUF) * 24576 + n_ * 4096 + wb);                    \
        _Pragma("unroll")                                                         \
        for (int n_ = 0; n_ < 2; ++n_)                                            \
            async_cp16(W + goffB[n_] + (KT) * 64,                                 \
                       smem + (BUF) * 24576 + 16384 + n_ * 4096 + wb);            \
    } while (0)

    f32x4 acc[4][2];
    #pragma unroll
    for (int fr = 0; fr < 4; ++fr)
        #pragma unroll
        for (int fc = 0; fc < 2; ++fc) acc[fr][fc] = (f32x4)0.0f;

    GSTAGE(0, 0);
    int buf = 0;
    const int KS = KD / 64;
    for (int kt = 0; kt < KS; ++kt) {
        if (kt < KS - 1) {
            GSTAGE(buf ^ 1, kt + 1);
            asm volatile("s_waitcnt vmcnt(6)" ::: "memory");
        } else {
            asm volatile("s_waitcnt vmcnt(0)" ::: "memory");
        }
        __builtin_amdgcn_s_barrier();
        asm volatile("" ::: "memory");
        const char* Ab = smem + buf * 24576;
        const char* Bb = smem + buf * 24576 + 16384;
        #pragma unroll
        for (int kk = 0; kk < 2; ++kk) {
            bf16x8 af[4], bf[2];
            #pragma unroll
            for (int fr = 0; fr < 4; ++fr) {
                int row = wr * 64 + fr * 16 + r;
                af[fr] = *(const bf16x8*)(Ab + row * 128 + (((kk * 4 + h) ^ (row & 7)) << 4));
            }
            #pragma unroll
            for (int fc = 0; fc < 2; ++fc) {
                int rowb = wc * 32 + fc * 16 + r;
                bf[fc] = *(const bf16x8*)(Bb + rowb * 128 + (((kk * 4 + h) ^ (rowb & 7)) << 4));
            }
            #pragma unroll
            for (int fr = 0; fr < 4; ++fr)
                #pragma unroll
                for (int fc = 0; fc < 2; ++fc)
                    acc[fr][fc] = __builtin_amdgcn_mfma_f32_16x16x32_bf16(
                        af[fr], bf[fc], acc[fr][fc], 0, 0, 0);
        }
        asm volatile("" ::: "memory");
        __builtin_amdgcn_s_barrier();
        asm volatile("" ::: "memory");
        buf ^= 1;
    }
    #undef GSTAGE

    const int mw = m0 + wr * 64;
    const int ob0 = bn0 + wc * 32;

    if (EPI == 0) {
        u16* out = (u16*)outp;
        #pragma unroll
        for (int fc = 0; fc < 2; ++fc) {
            int o = ob0 + fc * 16 + r;
            float bs = bias[o];
            #pragma unroll
            for (int fr = 0; fr < 4; ++fr)
                #pragma unroll
                for (int rr = 0; rr < 4; ++rr) {
                    int mrow = mw + fr * 16 + h * 4 + rr;
                    out[(size_t)mrow * NOUT + o] = f2b((acc[fr][fc][rr] + bs) * alpha);
                }
        }
    } else if (EPI == 1) {
        // transpose via LDS then store in MFMA-fragment order V'[b][ct][j16][lane][8]
        u16* tile = (u16*)(smem + wave * 4608);
        #pragma unroll
        for (int fc = 0; fc < 2; ++fc) {
            int o = ob0 + fc * 16 + r;
            float bs = bias[o];
            #pragma unroll
            for (int fr = 0; fr < 4; ++fr) {
                u16x4 v4;
                #pragma unroll
                for (int rr = 0; rr < 4; ++rr) v4[rr] = f2b(acc[fr][fc][rr] + bs);
                *(u16x4*)(tile + (fc * 16 + r) * 72 + fr * 16 + h * 4) = v4;
            }
        }
        __builtin_amdgcn_s_waitcnt(0);
        u16* Vout = (u16*)outp;
        int bb = mw >> 12, nb = mw & 4095;
        #pragma unroll
        for (int g = 0; g < 4; ++g) {
            int chunk = g * 64 + lane;
            int row = chunk >> 3, ns = chunk & 7;
            int ch = ob0 + row;
            int j = nb + ns * 8;
            bf16x8 val = *(const bf16x8*)(tile + row * 72 + ns * 8);
            size_t off = (size_t)bb * CU * NN + (size_t)(ch >> 5) * (NN * 32)
                       + (size_t)(j >> 4) * 512
                       + (size_t)((ch & 31) + ((j >> 3) & 1) * 32) * 8 + (j & 7);
            *(bf16x8*)(Vout + off) = val;
        }
    } else {
        float* tile = (float*)(smem + wave * 8704);   // [32][68] f32
        #pragma unroll
        for (int fc = 0; fc < 2; ++fc)
            #pragma unroll
            for (int fr = 0; fr < 4; ++fr)
                *(f32x4*)(tile + (fc * 16 + r) * 68 + fr * 16 + h * 4) = acc[fr][fc];
        __builtin_amdgcn_s_waitcnt(0);
        float* out = (float*)outp;
        int bb = mw >> 12, nb = mw & 4095;
        #pragma unroll
        for (int g = 0; g < 8; ++g) {
            int chunk = g * 64 + lane;
            int row = chunk >> 4, ns = chunk & 15;
            int o = ob0 + row;
            size_t base = (size_t)bb * CU * NN + (size_t)o * NN + nb + ns * 4;
            f32x4 v = *(const f32x4*)(tile + row * 68 + ns * 4);
            f32x4 u = *(const f32x4*)(unet + base);
            float bs = bias[o];
            f32x4 res;
            #pragma unroll
            for (int rr = 0; rr < 4; ++rr) res[rr] = v[rr] + bs + u[rr];
            *(f32x4*)(out + base) = res;
        }
    }
}

// ---------------- flash attention (round-7: software-pipelined) ----------------
// Q: [B][N][256] bf16 (pre-scaled log2e/16), K: [B][N][256],
// V': [B][ct 10][j16 256][lane 64][8] bf16 (fragment order).
// grid 512 (32-row i-tiles), 4 waves: cw (160-ch half) x jw (32-j slice).
// Pipeline: body i does QK(i+1) [MFMA] + softmax(i) [VALU] + PV(i) [MFMA];
// ONE barrier per body; own-stage drained by vmcnt(0) at body end.
__global__ __launch_bounds__(256, 2) void attn_kernel(
        const u16* __restrict__ Q, const u16* __restrict__ K,
        const u16* __restrict__ V, u16* __restrict__ AO) {
    __shared__ __align__(16) char smem[66048];

    const int t = threadIdx.x;
    const int lane = t & 63;
    const int wave = t >> 6;
    const int cw = wave >> 1;
    const int jw = wave & 1;
    const int r = lane & 31, hi = lane >> 5;

    int linear = blockIdx.x;
    int swz = (linear & 7) * 64 + (linear >> 3);
    int b = swz >> 7;
    int i0 = (swz & 127) * 32;

    const u16* Qb = Q + ((size_t)b * NN + i0) * AD;
    const u16* Kb = K + (size_t)b * NN * AD;
    const u16* Vb = V + (size_t)b * CU * NN;

    int goff[8];
    #pragma unroll
    for (int n = 0; n < 8; ++n) {
        int c = n * 256 + t;
        int half = n >> 2;
        int rowl = (c >> 5) & 31;
        int c16 = c & 31;
        goff[n] = (half * 32 + rowl) * 256 + ((c16 ^ rowl) << 3);
    }
    const unsigned wb = (unsigned)(t & ~63) * 16u;

    #define STAGE(BUF, KP) do {                                                   \
        _Pragma("unroll")                                                         \
        for (int n_ = 0; n_ < 8; ++n_)                                            \
            async_cp16((KP) + goff[n_], smem + (BUF) * 32768 + n_ * 4096 + wb);   \
    } while (0)

    // Q fragments (B-operand: col = q-row = r, k = kk*16 + hi*8 + e)
    bf16x8 q[16];
    #pragma unroll
    for (int kk = 0; kk < 16; ++kk)
        q[kk] = *(const bf16x8*)(Qb + (size_t)r * AD + kk * 16 + hi * 8);

    f32x16 o[5];
    #pragma unroll
    for (int ct = 0; ct < 5; ++ct) o[ct] = (f32x16)0.0f;
    float m = -INFINITY, lsum = 0.0f;

    // V' per-wave base
    const u16* vbase = Vb + (size_t)(cw * 5) * (NN * 32) + (jw * 2) * 512 + lane * 8;

    // ---- prologue: stage K[0], K[1]; compute QK(0) ----
    STAGE(0, Kb);
    STAGE(1, Kb + 16384);
    asm volatile("s_waitcnt vmcnt(8)" ::: "memory");   // own K[0] done
    __builtin_amdgcn_s_barrier();                      // all waves' K[0] done
    asm volatile("" ::: "memory");

    f32x16 sc;                                          // carried scores S(i)
    {
        const char* Kt = smem + jw * 16384;             // buf0
        f32x16 acc0 = (f32x16)0.0f;
        __builtin_amdgcn_s_setprio(1);
        #pragma unroll
        for (int kk = 0; kk < 16; ++kk) {
            bf16x8 k0 = *(const bf16x8*)(Kt + r * 512 + (((kk * 2 + hi) ^ r) << 4));
            acc0 = __builtin_amdgcn_mfma_f32_32x32x16_bf16(k0, q[kk], acc0, 0, 0, 0);
        }
        __builtin_amdgcn_s_setprio(0);
        sc = acc0;
    }
    asm volatile("s_waitcnt vmcnt(0)" ::: "memory");    // own K[1] done

    // ---- main pipelined loop: body i handles QK(i+1), softmax(i), PV(i) ----
    for (int i = 0; i < 63; ++i) {
        __builtin_amdgcn_s_barrier();                   // all waves done body i-1
        asm volatile("" ::: "memory");

        if (i <= 61) STAGE((i & 1), Kb + (i + 2) * 16384);

        // V fragments for THIS body's PV (coalesced, from fragment-ordered V')
        bf16x8 vf[10];
        #pragma unroll
        for (int ks = 0; ks < 2; ++ks)
            #pragma unroll
            for (int ct = 0; ct < 5; ++ct)
                vf[ks * 5 + ct] = *(const bf16x8*)(
                    vbase + (size_t)ct * (NN * 32) + (size_t)(i * 4 + ks) * 512);

        // ---- QK(i+1) [MFMA pipe] ----
        const char* Kt = smem + ((i + 1) & 1) * 32768 + jw * 16384;
        f32x16 sn = (f32x16)0.0f;
        __builtin_amdgcn_s_setprio(1);
        #pragma unroll
        for (int kk = 0; kk < 16; ++kk) {
            bf16x8 k0 = *(const bf16x8*)(Kt + r * 512 + (((kk * 2 + hi) ^ r) << 4));
            sn = __builtin_amdgcn_mfma_f32_32x32x16_bf16(k0, q[kk], sn, 0, 0, 0);
        }
        __builtin_amdgcn_s_setprio(0);

        // ---- softmax(i) on carried sc [VALU pipe, overlaps QK chain] ----
        float x0 = fmaxf(sc[0], sc[1]),   x1 = fmaxf(sc[2], sc[3]);
        float x2 = fmaxf(sc[4], sc[5]),   x3 = fmaxf(sc[6], sc[7]);
        float x4 = fmaxf(sc[8], sc[9]),   x5 = fmaxf(sc[10], sc[11]);
        float x6 = fmaxf(sc[12], sc[13]), x7 = fmaxf(sc[14], sc[15]);
        float pmax = fmaxf(fmaxf(fmaxf(x0, x1), fmaxf(x2, x3)),
                           fmaxf(fmaxf(x4, x5), fmaxf(x6, x7)));
        pmax = fmaxf(pmax, __shfl_xor(pmax, 32));
        if (__any(pmax > m + 8.0f)) {
            float mn = fmaxf(m, pmax);
            float al = exp2_fast(m - mn);
            m = mn;
            lsum *= al;
            #pragma unroll
            for (int ct = 0; ct < 5; ++ct) o[ct] *= al;
        }
        float p[16];
        #pragma unroll
        for (int e = 0; e < 16; ++e) p[e] = exp2_fast(sc[e] - m);
        float y0 = (p[0] + p[1]) + (p[2] + p[3]);
        float y1 = (p[4] + p[5]) + (p[6] + p[7]);
        float y2 = (p[8] + p[9]) + (p[10] + p[11]);
        float y3 = (p[12] + p[13]) + (p[14] + p[15]);
        float ps = (y0 + y1) + (y2 + y3);
        ps += __shfl_xor(ps, 32);
        lsum += ps;

        // ---- PV(i) ----
        __builtin_amdgcn_s_setprio(1);
        #pragma unroll
        for (int ks = 0; ks < 2; ++ks) {
            unsigned a0 = cvt_pk_bf16(p[8 * ks + 0], p[8 * ks + 1]);
            unsigned a1 = cvt_pk_bf16(p[8 * ks + 2], p[8 * ks + 3]);
            unsigned b0 = cvt_pk_bf16(p[8 * ks + 4], p[8 * ks + 5]);
            unsigned b1 = cvt_pk_bf16(p[8 * ks + 6], p[8 * ks + 7]);
            asm("v_permlane32_swap_b32 %0, %1" : "+v"(a0), "+v"(b0));
            asm("v_permlane32_swap_b32 %0, %1" : "+v"(a1), "+v"(b1));
            union { unsigned w[4]; bf16x8 v; } u;
            u.w[0] = a0; u.w[1] = a1; u.w[2] = b0; u.w[3] = b1;
            #pragma unroll
            for (int ct = 0; ct < 5; ++ct)
                o[ct] = __builtin_amdgcn_mfma_f32_32x32x16_bf16(
                    vf[ks * 5 + ct], u.v, o[ct], 0, 0, 0);
        }
        __builtin_amdgcn_s_setprio(0);

        sc = sn;
        asm volatile("s_waitcnt vmcnt(0)" ::: "memory");  // own K[i+2] done (free)
    }

    // ---- tail body 63: softmax(63) + PV(63), no QK/stage/barrier ----
    {
        bf16x8 vf[10];
        #pragma unroll
        for (int ks = 0; ks < 2; ++ks)
            #pragma unroll
            for (int ct = 0; ct < 5; ++ct)
                vf[ks * 5 + ct] = *(const bf16x8*)(
                    vbase + (size_t)ct * (NN * 32) + (size_t)(63 * 4 + ks) * 512);
        float x0 = fmaxf(sc[0], sc[1]),   x1 = fmaxf(sc[2], sc[3]);
        float x2 = fmaxf(sc[4], sc[5]),   x3 = fmaxf(sc[6], sc[7]);
        float x4 = fmaxf(sc[8], sc[9]),   x5 = fmaxf(sc[10], sc[11]);
        float x6 = fmaxf(sc[12], sc[13]), x7 = fmaxf(sc[14], sc[15]);
        float pmax = fmaxf(fmaxf(fmaxf(x0, x1), fmaxf(x2, x3)),
                           fmaxf(fmaxf(x4, x5), fmaxf(x6, x7)));
        pmax = fmaxf(pmax, __shfl_xor(pmax, 32));
        if (__any(pmax > m + 8.0f)) {
            float mn = fmaxf(m, pmax);
            float al = exp2_fast(m - mn);
            m = mn;
            lsum *= al;
            #pragma unroll
            for (int ct = 0; ct < 5; ++ct) o[ct] *= al;
        }
        float p[16];
        #pragma unroll
        for (int e = 0; e < 16; ++e) p[e] = exp2_fast(sc[e] - m);
        float y0 = (p[0] + p[1]) + (p[2] + p[3]);
        float y1 = (p[4] + p[5]) + (p[6] + p[7]);
        float y2 = (p[8] + p[9]) + (p[10] + p[11]);
        float y3 = (p[12] + p[13]) + (p[14] + p[15]);
        float ps = (y0 + y1) + (y2 + y3);
        ps += __shfl_xor(ps, 32);
        lsum += ps;
        #pragma unroll
        for (int ks = 0; ks < 2; ++ks) {
            unsigned a0 = cvt_pk_bf16(p[8 * ks + 0], p[8 * ks + 1]);
            unsigned a1 = cvt_pk_bf16(p[8 * ks + 2], p[8 * ks + 3]);
            unsigned b0 = cvt_pk_bf16(p[8 * ks + 4], p[8 * ks + 5]);
            unsigned b1 = cvt_pk_bf16(p[8 * ks + 6], p[8 * ks + 7]);
            asm("v_permlane32_swap_b32 %0, %1" : "+v"(a0), "+v"(b0));
            asm("v_permlane32_swap_b32 %0, %1" : "+v"(a1), "+v"(b1));
            union { unsigned w[4]; bf16x8 v; } u;
            u.w[0] = a0; u.w[1] = a1; u.w[2] = b0; u.w[3] = b1;
            #pragma unroll
            for (int ct = 0; ct < 5; ++ct)
                o[ct] = __builtin_amdgcn_mfma_f32_32x32x16_bf16(
                    vf[ks * 5 + ct], u.v, o[ct], 0, 0, 0);
        }
    }

    // ---- merge jw halves (cross-wave LDS: __syncthreads, race-free) ----
    float* mlb = (float*)(smem + 65536);
    if (cw == 0 && lane < 32) {
        mlb[jw * 32 + r] = m;
        mlb[64 + jw * 32 + r] = lsum;
    }
    __syncthreads();
    float mo = mlb[(jw ^ 1) * 32 + r];
    float lo = mlb[64 + (jw ^ 1) * 32 + r];
    float M = fmaxf(m, mo);
    float f = exp2_fast(m - M);
    float fo = exp2_fast(mo - M);
    float inv = 1.0f / (lsum * f + lo * fo);

    float* fb = (float*)smem;              // [32][321] f32
    if (jw == 1) {
        #pragma unroll
        for (int ct = 0; ct < 5; ++ct)
            #pragma unroll
            for (int e = 0; e < 16; ++e) {
                int c = cw * 160 + ct * 32 + (e & 3) + 8 * (e >> 2) + 4 * hi;
                fb[r * 321 + c] = o[ct][e] * f;
            }
    }
    __syncthreads();
    u16* ob = (u16*)(smem + 41088);        // [32][328] u16
    if (jw == 0) {
        #pragma unroll
        for (int ct = 0; ct < 5; ++ct)
            #pragma unroll
            for (int g = 0; g < 4; ++g) {
                int cb = cw * 160 + ct * 32 + 8 * g + 4 * hi;
                const float* fr = &fb[r * 321 + cb];
                float v0 = (o[ct][4 * g + 0] * f + fr[0]) * inv;
                float v1 = (o[ct][4 * g + 1] * f + fr[1]) * inv;
                float v2 = (o[ct][4 * g + 2] * f + fr[2]) * inv;
                float v3 = (o[ct][4 * g + 3] * f + fr[3]) * inv;
                *(unsigned*)(ob + r * 328 + cb) = cvt_pk_bf16(v0, v1);
                *(unsigned*)(ob + r * 328 + cb + 2) = cvt_pk_bf16(v2, v3);
            }
    }
    __syncthreads();

    u16* AOb = AO + ((size_t)b * NN + i0) * CU;
    #pragma unroll
    for (int n = 0; n < 5; ++n) {
        int id = n * 256 + t;
        int row = id / 40, c8 = id % 40;
        bf16x8 val = *(const bf16x8*)(ob + row * 328 + c8 * 8);
        *(bf16x8*)(AOb + (size_t)row * CU + c8 * 8) = val;
    }
    #undef STAGE
}

extern "C" void kernel_launch(void* const* d_in, const int* in_sizes, int n_in,
                              void* d_out, int out_size, void* d_ws, size_t ws_size,
                              hipStream_t stream) {
    const float* unet  = (const float*)d_in[0];
    const float* janus = (const float*)d_in[1];
    const float* Wq = (const float*)d_in[2];
    const float* bq = (const float*)d_in[3];
    const float* Wk = (const float*)d_in[4];
    const float* bk = (const float*)d_in[5];
    const float* Wv = (const float*)d_in[6];
    const float* bv = (const float*)d_in[7];
    const float* Wo = (const float*)d_in[8];
    const float* bo = (const float*)d_in[9];
    float* out = (float*)d_out;

    char* ws = (char*)d_ws;
    u16* Xu  = (u16*)(ws + XU_OFF);
    u16* Xj  = (u16*)(ws + XJ_OFF);
    u16* Qb  = (u16*)(ws + QB_OFF);
    u16* Kb  = (u16*)(ws + KB_OFF);
    u16* Vb  = (u16*)(ws + VB_OFF);
    u16* wq  = (u16*)(ws + WQ_OFF);
    u16* wk  = (u16*)(ws + WK_OFF);
    u16* wv  = (u16*)(ws + WV_OFF);
    u16* wo  = (u16*)(ws + WO_OFF);
    u16* AO  = (u16*)(ws + AO_OFF);

    wcast_kernel<<<3024, 256, 0, stream>>>(Wq, Wk, Wv, Wo, wq, wk, wv, wo);

    transpose_cast_kernel<<<dim3(64, 5, NB), 256, 0, stream>>>(unet, Xu, CU, NN);
    transpose_cast_kernel<<<dim3(64, 16, NB), 256, 0, stream>>>(janus, Xj, CJ, NN);

    // Q pre-scaled by (1/16) * log2(e) so softmax runs in exp2 domain
    gemm_kernel<0, 320, 256><<<dim3(128, 4), 256, 0, stream>>>(
        Xu, wq, bq, Qb, nullptr, 0.0901684411f);
    gemm_kernel<0, 1024, 256><<<dim3(128, 4), 256, 0, stream>>>(
        Xj, wk, bk, Kb, nullptr, 1.0f);
    gemm_kernel<1, 1024, 320><<<dim3(128, 5), 256, 0, stream>>>(
        Xj, wv, bv, Vb, nullptr, 1.0f);

    attn_kernel<<<512, 256, 0, stream>>>(Qb, Kb, Vb, AO);

    gemm_kernel<2, 320, 320><<<dim3(128, 5), 256, 0, stream>>>(
        AO, wo, bo, out, unet, 1.0f);
}

// Round 9
// 244.715 us; speedup vs baseline: 1.1177x; 1.1177x over previous
//
#include <hip/hip_runtime.h>
#include <hip/hip_bf16.h>
#include <math.h>

// ---------------------------------------------------------------------------
// CrossModalAttention on MI355X (gfx950)
//   B=4, Cu=320, Cj=1024, H=W=64 (N=4096), ATTN_DIM=256, scale = 1/16
// Round 8: producer-consumer wave specialization in attn.
//   384-thread blocks, 6 waves: 2 QK waves (jw halves: QK+softmax+P-write in
//   B-fragment layout) and 4 PV waves (jw x ch-half: P-frag read + coalesced
//   V' + o accumulation). P/al/flag parity-double-buffered in LDS; one
//   s_barrier per tile; lgkmcnt(0) drain before barriers; disjoint role loops
//   for separate register pools; __launch_bounds__(384,3) -> 12 waves/CU.
// ---------------------------------------------------------------------------

typedef unsigned short u16;
typedef __attribute__((ext_vector_type(8))) short bf16x8;
typedef __attribute__((ext_vector_type(4))) float f32x4;
typedef __attribute__((ext_vector_type(16))) float f32x16;
typedef __attribute__((ext_vector_type(4))) unsigned short u16x4;

#define NB 4
#define CU 320
#define CJ 1024
#define NN 4096
#define AD 256

// ws layout (bytes)
#define XU_OFF 0u
#define XJ_OFF 10485760u
#define QB_OFF 44040192u
#define KB_OFF 52428800u
#define VB_OFF 60817408u
#define WQ_OFF 71303168u
#define WK_OFF 71467008u
#define WV_OFF 71991296u
#define WO_OFF 72646656u
#define AO_OFF XU_OFF

__device__ __forceinline__ u16 f2b(float f) {
    union { float f; unsigned u; } v; v.f = f;
    unsigned u = v.u;
    unsigned r = (u + 0x7fffu + ((u >> 16) & 1u)) >> 16;
    return (u16)r;
}

__device__ __forceinline__ unsigned cvt_pk_bf16(float lo, float hi) {
    unsigned r;
    asm("v_cvt_pk_bf16_f32 %0, %1, %2" : "=v"(r) : "v"(lo), "v"(hi));
    return r;
}

__device__ __forceinline__ float exp2_fast(float x) {
    float r;
    asm("v_exp_f32 %0, %1" : "=v"(r) : "v"(x));
    return r;
}

__device__ __forceinline__ void async_cp16(const u16* g, char* l) {
    __builtin_amdgcn_global_load_lds(
        (const __attribute__((address_space(1))) unsigned int*)g,
        (__attribute__((address_space(3))) unsigned int*)l, 16, 0, 0);
}

// ---------------- weight cast ----------------
__global__ void wcast_kernel(const float* __restrict__ Wq, const float* __restrict__ Wk,
                             const float* __restrict__ Wv, const float* __restrict__ Wo,
                             u16* __restrict__ wq, u16* __restrict__ wk,
                             u16* __restrict__ wv, u16* __restrict__ wo) {
    int id = blockIdx.x * 256 + threadIdx.x;
    if (id < 81920) { wq[id] = f2b(Wq[id]); return; }
    id -= 81920;
    if (id < 262144) { wk[id] = f2b(Wk[id]); return; }
    id -= 262144;
    if (id < 327680) { wv[id] = f2b(Wv[id]); return; }
    id -= 327680;
    if (id < 102400) { wo[id] = f2b(Wo[id]); }
}

// ---------------- transpose [C][N] f32 -> [N][C] bf16 ----------------
__global__ __launch_bounds__(256) void transpose_cast_kernel(
        const float* __restrict__ in, u16* __restrict__ out, int C, int Nn) {
    __shared__ float tile[64][65];
    int b = blockIdx.z;
    int n0 = blockIdx.x * 64, c0 = blockIdx.y * 64;
    const float* src = in + (size_t)b * C * Nn;
    u16* dst = out + (size_t)b * Nn * C;
    int t = threadIdx.x;
    int nl = t & 63, cl = t >> 6;
    #pragma unroll
    for (int k = 0; k < 16; ++k) {
        int c = cl + k * 4;
        tile[c][nl] = src[(size_t)(c0 + c) * Nn + n0 + nl];
    }
    __syncthreads();
    int cl2 = t & 63, nl2 = t >> 6;
    #pragma unroll
    for (int k = 0; k < 16; ++k) {
        int n = nl2 + k * 4;
        dst[(size_t)(n0 + n) * C + c0 + cl2] = f2b(tile[cl2][n]);
    }
}

// ---------------- unified GEMM: out = A(16384xKD) @ W(NOUTxKD)^T ----------------
template <int EPI, int KD, int NOUT>
__global__ __launch_bounds__(256, 2) void gemm_kernel(
        const u16* __restrict__ A, const u16* __restrict__ W,
        const float* __restrict__ bias, void* __restrict__ outp,
        const float* __restrict__ unet, float alpha) {
    __shared__ __align__(16) char smem[49152];
    const int t = threadIdx.x;
    const int lane = t & 63, wave = t >> 6;
    const int r = lane & 15, h = lane >> 4;
    const int wr = wave >> 1, wc = wave & 1;
    const int m0 = blockIdx.x * 128;
    const int bn0 = blockIdx.y * 64;

    int goffA[4], goffB[2];
    #pragma unroll
    for (int n = 0; n < 4; ++n) {
        int c = n * 256 + t;
        int row = c >> 3, s = c & 7;
        goffA[n] = (m0 + row) * KD + ((s ^ (row & 7)) << 3);
    }
    #pragma unroll
    for (int n = 0; n < 2; ++n) {
        int c = n * 256 + t;
        int row = c >> 3, s = c & 7;
        goffB[n] = (bn0 + row) * KD + ((s ^ (row & 7)) << 3);
    }
    const unsigned wb = (unsigned)(t & ~63) * 16u;

    #define GSTAGE(BUF, KT) do {                                                  \
        _Pragma("unroll")                                                         \
        for (int n_ = 0; n_ < 4; ++n_)                                            \
            async_cp16(A + goffA[n_] + (KT) * 64,                                 \
                       smem + (BUF) * 24576 + n_ * 4096 + wb);                    \
        _Pragma("unroll")                                                         \
        for (int n_ = 0; n_ < 2; ++n_)                                            \
            async_cp16(W + goffB[n_] + (KT) * 64,                                 \
                       smem + (BUF) * 24576 + 16384 + n_ * 4096 + wb);            \
    } while (0)

    f32x4 acc[4][2];
    #pragma unroll
    for (int fr = 0; fr < 4; ++fr)
        #pragma unroll
        for (int fc = 0; fc < 2; ++fc) acc[fr][fc] = (f32x4)0.0f;

    GSTAGE(0, 0);
    int buf = 0;
    const int KS = KD / 64;
    for (int kt = 0; kt < KS; ++kt) {
        if (kt < KS - 1) {
            GSTAGE(buf ^ 1, kt + 1);
            asm volatile("s_waitcnt vmcnt(6)" ::: "memory");
        } else {
            asm volatile("s_waitcnt vmcnt(0)" ::: "memory");
        }
        __builtin_amdgcn_s_barrier();
        asm volatile("" ::: "memory");
        const char* Ab = smem + buf * 24576;
        const char* Bb = smem + buf * 24576 + 16384;
        #pragma unroll
        for (int kk = 0; kk < 2; ++kk) {
            bf16x8 af[4], bf[2];
            #pragma unroll
            for (int fr = 0; fr < 4; ++fr) {
                int row = wr * 64 + fr * 16 + r;
                af[fr] = *(const bf16x8*)(Ab + row * 128 + (((kk * 4 + h) ^ (row & 7)) << 4));
            }
            #pragma unroll
            for (int fc = 0; fc < 2; ++fc) {
                int rowb = wc * 32 + fc * 16 + r;
                bf[fc] = *(const bf16x8*)(Bb + rowb * 128 + (((kk * 4 + h) ^ (rowb & 7)) << 4));
            }
            #pragma unroll
            for (int fr = 0; fr < 4; ++fr)
                #pragma unroll
                for (int fc = 0; fc < 2; ++fc)
                    acc[fr][fc] = __builtin_amdgcn_mfma_f32_16x16x32_bf16(
                        af[fr], bf[fc], acc[fr][fc], 0, 0, 0);
        }
        asm volatile("" ::: "memory");
        __builtin_amdgcn_s_barrier();
        asm volatile("" ::: "memory");
        buf ^= 1;
    }
    #undef GSTAGE

    const int mw = m0 + wr * 64;
    const int ob0 = bn0 + wc * 32;

    if (EPI == 0) {
        u16* out = (u16*)outp;
        #pragma unroll
        for (int fc = 0; fc < 2; ++fc) {
            int o = ob0 + fc * 16 + r;
            float bs = bias[o];
            #pragma unroll
            for (int fr = 0; fr < 4; ++fr)
                #pragma unroll
                for (int rr = 0; rr < 4; ++rr) {
                    int mrow = mw + fr * 16 + h * 4 + rr;
                    out[(size_t)mrow * NOUT + o] = f2b((acc[fr][fc][rr] + bs) * alpha);
                }
        }
    } else if (EPI == 1) {
        // transpose via LDS then store in MFMA-fragment order V'[b][ct][j16][lane][8]
        u16* tile = (u16*)(smem + wave * 4608);
        #pragma unroll
        for (int fc = 0; fc < 2; ++fc) {
            int o = ob0 + fc * 16 + r;
            float bs = bias[o];
            #pragma unroll
            for (int fr = 0; fr < 4; ++fr) {
                u16x4 v4;
                #pragma unroll
                for (int rr = 0; rr < 4; ++rr) v4[rr] = f2b(acc[fr][fc][rr] + bs);
                *(u16x4*)(tile + (fc * 16 + r) * 72 + fr * 16 + h * 4) = v4;
            }
        }
        __builtin_amdgcn_s_waitcnt(0);
        u16* Vout = (u16*)outp;
        int bb = mw >> 12, nb = mw & 4095;
        #pragma unroll
        for (int g = 0; g < 4; ++g) {
            int chunk = g * 64 + lane;
            int row = chunk >> 3, ns = chunk & 7;
            int ch = ob0 + row;
            int j = nb + ns * 8;
            bf16x8 val = *(const bf16x8*)(tile + row * 72 + ns * 8);
            size_t off = (size_t)bb * CU * NN + (size_t)(ch >> 5) * (NN * 32)
                       + (size_t)(j >> 4) * 512
                       + (size_t)((ch & 31) + ((j >> 3) & 1) * 32) * 8 + (j & 7);
            *(bf16x8*)(Vout + off) = val;
        }
    } else {
        float* tile = (float*)(smem + wave * 8704);   // [32][68] f32
        #pragma unroll
        for (int fc = 0; fc < 2; ++fc)
            #pragma unroll
            for (int fr = 0; fr < 4; ++fr)
                *(f32x4*)(tile + (fc * 16 + r) * 68 + fr * 16 + h * 4) = acc[fr][fc];
        __builtin_amdgcn_s_waitcnt(0);
        float* out = (float*)outp;
        int bb = mw >> 12, nb = mw & 4095;
        #pragma unroll
        for (int g = 0; g < 8; ++g) {
            int chunk = g * 64 + lane;
            int row = chunk >> 4, ns = chunk & 15;
            int o = ob0 + row;
            size_t base = (size_t)bb * CU * NN + (size_t)o * NN + nb + ns * 4;
            f32x4 v = *(const f32x4*)(tile + row * 68 + ns * 4);
            f32x4 u = *(const f32x4*)(unet + base);
            float bs = bias[o];
            f32x4 res;
            #pragma unroll
            for (int rr = 0; rr < 4; ++rr) res[rr] = v[rr] + bs + u[rr];
            *(f32x4*)(out + base) = res;
        }
    }
}

// ---------------- flash attention (round-8: wave specialization) ----------------
// Q: [B][N][256] bf16 (pre-scaled log2e/16), K: [B][N][256],
// V': [B][ct 10][j16 256][lane 64][8] bf16 (fragment order).
// 512 blocks x 384 thr (6 waves): waves 0-1 = QK(jw), waves 2-5 = PV(pj,pc).
// LDS: kbuf 2x32KB @0; pbuf parity @65536 (+par*4608): frags [jw][ks][lane]16B,
//      al @+4096 [jw][32]f32, flag @+4352 [jw]u32; mlb @74752.
__global__ __launch_bounds__(384, 3) void attn_kernel(
        const u16* __restrict__ Q, const u16* __restrict__ K,
        const u16* __restrict__ V, u16* __restrict__ AO) {
    __shared__ __align__(16) char smem[75264];

    const int t = threadIdx.x;
    const int lane = t & 63;
    const int wave = t >> 6;          // 0..5
    const int r = lane & 31, hi = lane >> 5;

    int linear = blockIdx.x;
    int swz = (linear & 7) * 64 + (linear >> 3);
    int b = swz >> 7;
    int i0 = (swz & 127) * 32;

    const u16* Qb = Q + ((size_t)b * NN + i0) * AD;
    const u16* Kb = K + (size_t)b * NN * AD;
    const u16* Vb = V + (size_t)b * CU * NN;

    // K staging: 64j x 256ch tile = 2048 chunks of 16B over 384 threads
    int goff[6];
    unsigned ldsoff[6];
    #pragma unroll
    for (int n = 0; n < 6; ++n) {
        int id = n * 384 + t;
        int row = (id >> 5) & 63;
        int c16 = id & 31;
        goff[n] = row * 256 + ((c16 ^ (row & 31)) << 3);
        ldsoff[n] = (unsigned)(n * 384 + (t & ~63)) * 16u;
    }

    #define STAGE(BUF, KP) do {                                                   \
        _Pragma("unroll")                                                         \
        for (int n_ = 0; n_ < 5; ++n_)                                            \
            async_cp16((KP) + goff[n_], smem + (BUF) * 32768 + ldsoff[n_]);       \
        if (t < 128)                                                              \
            async_cp16((KP) + goff[5], smem + (BUF) * 32768 + ldsoff[5]);         \
    } while (0)

    STAGE(0, Kb);
    asm volatile("s_waitcnt vmcnt(0)" ::: "memory");

    if (wave < 2) {
        // ================= QK role =================
        const int jw = wave;
        bf16x8 q[16];
        #pragma unroll
        for (int kk = 0; kk < 16; ++kk)
            q[kk] = *(const bf16x8*)(Qb + (size_t)r * AD + kk * 16 + hi * 8);
        float m = -INFINITY, lsum = 0.0f;

        for (int i = 0; i < 64; ++i) {
            __builtin_amdgcn_s_barrier();
            asm volatile("" ::: "memory");
            if (i < 63) STAGE((i + 1) & 1, Kb + (i + 1) * 16384);

            const char* Kt = smem + (i & 1) * 32768 + jw * 16384;
            f32x16 sa = (f32x16)0.0f, sb = (f32x16)0.0f;
            __builtin_amdgcn_s_setprio(1);
            #pragma unroll
            for (int kk = 0; kk < 8; ++kk) {
                bf16x8 k0 = *(const bf16x8*)(Kt + r * 512 + (((2 * kk + hi) ^ r) << 4));
                bf16x8 k1 = *(const bf16x8*)(Kt + r * 512 + (((2 * (kk + 8) + hi) ^ r) << 4));
                sa = __builtin_amdgcn_mfma_f32_32x32x16_bf16(k0, q[kk], sa, 0, 0, 0);
                sb = __builtin_amdgcn_mfma_f32_32x32x16_bf16(k1, q[kk + 8], sb, 0, 0, 0);
            }
            __builtin_amdgcn_s_setprio(0);
            f32x16 s = sa + sb;

            // softmax (exp2 domain, defer-max THR=8)
            float x0 = fmaxf(s[0], s[1]),   x1 = fmaxf(s[2], s[3]);
            float x2 = fmaxf(s[4], s[5]),   x3 = fmaxf(s[6], s[7]);
            float x4 = fmaxf(s[8], s[9]),   x5 = fmaxf(s[10], s[11]);
            float x6 = fmaxf(s[12], s[13]), x7 = fmaxf(s[14], s[15]);
            float pmax = fmaxf(fmaxf(fmaxf(x0, x1), fmaxf(x2, x3)),
                               fmaxf(fmaxf(x4, x5), fmaxf(x6, x7)));
            pmax = fmaxf(pmax, __shfl_xor(pmax, 32));
            char* pb = smem + 65536 + (i & 1) * 4608;
            int fl = __any(pmax > m + 8.0f) ? 1 : 0;
            if (fl) {
                float mn = fmaxf(m, pmax);
                float al = exp2_fast(m - mn);
                m = mn;
                lsum *= al;
                if (lane < 32) *(float*)(pb + 4096 + jw * 128 + r * 4) = al;
            }
            if (lane == 0) *(int*)(pb + 4352 + jw * 4) = fl;
            float p[16];
            #pragma unroll
            for (int e = 0; e < 16; ++e) p[e] = exp2_fast(s[e] - m);
            float y0 = (p[0] + p[1]) + (p[2] + p[3]);
            float y1 = (p[4] + p[5]) + (p[6] + p[7]);
            float y2 = (p[8] + p[9]) + (p[10] + p[11]);
            float y3 = (p[12] + p[13]) + (p[14] + p[15]);
            float ps = (y0 + y1) + (y2 + y3);
            ps += __shfl_xor(ps, 32);
            lsum += ps;

            // P -> B-operand fragments, write to pbuf
            #pragma unroll
            for (int ks = 0; ks < 2; ++ks) {
                unsigned a0 = cvt_pk_bf16(p[8 * ks + 0], p[8 * ks + 1]);
                unsigned a1 = cvt_pk_bf16(p[8 * ks + 2], p[8 * ks + 3]);
                unsigned b0 = cvt_pk_bf16(p[8 * ks + 4], p[8 * ks + 5]);
                unsigned b1 = cvt_pk_bf16(p[8 * ks + 6], p[8 * ks + 7]);
                asm("v_permlane32_swap_b32 %0, %1" : "+v"(a0), "+v"(b0));
                asm("v_permlane32_swap_b32 %0, %1" : "+v"(a1), "+v"(b1));
                union { unsigned w[4]; bf16x8 v; } u;
                u.w[0] = a0; u.w[1] = a1; u.w[2] = b0; u.w[3] = b1;
                *(bf16x8*)(pb + jw * 2048 + ks * 1024 + lane * 16) = u.v;
            }
            asm volatile("s_waitcnt lgkmcnt(0)" ::: "memory");
            asm volatile("s_waitcnt vmcnt(0)" ::: "memory");
        }
        __builtin_amdgcn_s_barrier();   // #64: P(63) published
        asm volatile("" ::: "memory");
        // publish m/l
        if (lane < 32) {
            *(float*)(smem + 74752 + jw * 128 + r * 4) = m;
            *(float*)(smem + 74752 + 256 + jw * 128 + r * 4) = lsum;
        }
        __syncthreads();    // syncA
        __syncthreads();    // syncB
        __syncthreads();    // syncC
    } else {
        // ================= PV role =================
        const int pvid = wave - 2;
        const int pj = pvid & 1;        // which jw's P
        const int pc = pvid >> 1;       // 160-ch half
        f32x16 o[5];
        #pragma unroll
        for (int ct = 0; ct < 5; ++ct) o[ct] = (f32x16)0.0f;
        const u16* vb = Vb + (size_t)(pc * 5) * 131072 + lane * 8;

        #define PV_BODY(TI) do {                                                  \
            const char* pb = smem + 65536 + ((TI) & 1) * 4608;                    \
            int fl = *(volatile const int*)(pb + 4352 + pj * 4);                  \
            bf16x8 vfA[5], vfB[5];                                                \
            _Pragma("unroll")                                                     \
            for (int c = 0; c < 5; ++c)                                           \
                vfA[c] = *(const bf16x8*)(vb + (size_t)c * 131072 +               \
                                          ((TI) * 4 + pj * 2 + 0) * 512);         \
            _Pragma("unroll")                                                     \
            for (int c = 0; c < 5; ++c)                                           \
                vfB[c] = *(const bf16x8*)(vb + (size_t)c * 131072 +               \
                                          ((TI) * 4 + pj * 2 + 1) * 512);         \
            bf16x8 pf0 = *(const bf16x8*)(pb + pj * 2048 + lane * 16);            \
            bf16x8 pf1 = *(const bf16x8*)(pb + pj * 2048 + 1024 + lane * 16);     \
            if (fl) {                                                             \
                float alv = *(volatile const float*)(pb + 4096 + pj * 128 +       \
                                                     (lane & 31) * 4);            \
                _Pragma("unroll")                                                 \
                for (int ct = 0; ct < 5; ++ct) o[ct] *= alv;                      \
            }                                                                     \
            __builtin_amdgcn_s_setprio(1);                                        \
            _Pragma("unroll")                                                     \
            for (int ct = 0; ct < 5; ++ct)                                        \
                o[ct] = __builtin_amdgcn_mfma_f32_32x32x16_bf16(vfA[ct], pf0,     \
                                                                o[ct], 0, 0, 0); \
            _Pragma("unroll")                                                     \
            for (int ct = 0; ct < 5; ++ct)                                        \
                o[ct] = __builtin_amdgcn_mfma_f32_32x32x16_bf16(vfB[ct], pf1,     \
                                                                o[ct], 0, 0, 0); \
            __builtin_amdgcn_s_setprio(0);                                        \
        } while (0)

        for (int i = 0; i < 64; ++i) {
            __builtin_amdgcn_s_barrier();
            asm volatile("" ::: "memory");
            if (i < 63) STAGE((i + 1) & 1, Kb + (i + 1) * 16384);
            if (i >= 1) PV_BODY(i - 1);
            asm volatile("s_waitcnt vmcnt(0)" ::: "memory");
        }
        __builtin_amdgcn_s_barrier();   // #64: P(63) published
        asm volatile("" ::: "memory");
        PV_BODY(63);

        __syncthreads();    // syncA: m/l published, kbuf free
        // merge factors
        float m0 = *(const float*)(smem + 74752 + pj * 128 + r * 4);
        float l0 = *(const float*)(smem + 74752 + 256 + pj * 128 + r * 4);
        float m1 = *(const float*)(smem + 74752 + (pj ^ 1) * 128 + r * 4);
        float l1 = *(const float*)(smem + 74752 + 256 + (pj ^ 1) * 128 + r * 4);
        float M = fmaxf(m0, m1);
        float fsc = exp2_fast(m0 - M);
        float fo = exp2_fast(m1 - M);
        float inv = 1.0f / (l0 * fsc + l1 * fo);

        float* fb = (float*)smem;              // [32][321] f32
        if (pj == 1) {
            #pragma unroll
            for (int ct = 0; ct < 5; ++ct)
                #pragma unroll
                for (int e = 0; e < 16; ++e) {
                    int c = pc * 160 + ct * 32 + (e & 3) + 8 * (e >> 2) + 4 * hi;
                    fb[r * 321 + c] = o[ct][e] * fsc;
                }
        }
        __syncthreads();    // syncB
        u16* ob = (u16*)(smem + 41088);        // [32][328] u16
        if (pj == 0) {
            #pragma unroll
            for (int ct = 0; ct < 5; ++ct)
                #pragma unroll
                for (int g = 0; g < 4; ++g) {
                    int cb = pc * 160 + ct * 32 + 8 * g + 4 * hi;
                    const float* fr = &fb[r * 321 + cb];
                    float v0 = (o[ct][4 * g + 0] * fsc + fr[0]) * inv;
                    float v1 = (o[ct][4 * g + 1] * fsc + fr[1]) * inv;
                    float v2 = (o[ct][4 * g + 2] * fsc + fr[2]) * inv;
                    float v3 = (o[ct][4 * g + 3] * fsc + fr[3]) * inv;
                    *(unsigned*)(ob + r * 328 + cb) = cvt_pk_bf16(v0, v1);
                    *(unsigned*)(ob + r * 328 + cb + 2) = cvt_pk_bf16(v2, v3);
                }
        }
        __syncthreads();    // syncC
        #undef PV_BODY
    }

    // ---- common: store AO (32 q-rows x 320 ch) ----
    const u16* ob = (const u16*)(smem + 41088);
    u16* AOb = AO + ((size_t)b * NN + i0) * CU;
    #pragma unroll
    for (int n = 0; n < 3; ++n) {
        int id = n * 384 + t;
        int row = id / 40, c8 = id % 40;
        bf16x8 val = *(const bf16x8*)(ob + row * 328 + c8 * 8);
        *(bf16x8*)(AOb + (size_t)row * CU + c8 * 8) = val;
    }
    if (t < 128) {
        int id = 1152 + t;
        int row = id / 40, c8 = id % 40;
        bf16x8 val = *(const bf16x8*)(ob + row * 328 + c8 * 8);
        *(bf16x8*)(AOb + (size_t)row * CU + c8 * 8) = val;
    }
    #undef STAGE
}

extern "C" void kernel_launch(void* const* d_in, const int* in_sizes, int n_in,
                              void* d_out, int out_size, void* d_ws, size_t ws_size,
                              hipStream_t stream) {
    const float* unet  = (const float*)d_in[0];
    const float* janus = (const float*)d_in[1];
    const float* Wq = (const float*)d_in[2];
    const float* bq = (const float*)d_in[3];
    const float* Wk = (const float*)d_in[4];
    const float* bk = (const float*)d_in[5];
    const float* Wv = (const float*)d_in[6];
    const float* bv = (const float*)d_in[7];
    const float* Wo = (const float*)d_in[8];
    const float* bo = (const float*)d_in[9];
    float* out = (float*)d_out;

    char* ws = (char*)d_ws;
    u16* Xu  = (u16*)(ws + XU_OFF);
    u16* Xj  = (u16*)(ws + XJ_OFF);
    u16* Qb  = (u16*)(ws + QB_OFF);
    u16* Kb  = (u16*)(ws + KB_OFF);
    u16* Vb  = (u16*)(ws + VB_OFF);
    u16* wq  = (u16*)(ws + WQ_OFF);
    u16* wk  = (u16*)(ws + WK_OFF);
    u16* wv  = (u16*)(ws + WV_OFF);
    u16* wo  = (u16*)(ws + WO_OFF);
    u16* AO  = (u16*)(ws + AO_OFF);

    wcast_kernel<<<3024, 256, 0, stream>>>(Wq, Wk, Wv, Wo, wq, wk, wv, wo);

    transpose_cast_kernel<<<dim3(64, 5, NB), 256, 0, stream>>>(unet, Xu, CU, NN);
    transpose_cast_kernel<<<dim3(64, 16, NB), 256, 0, stream>>>(janus, Xj, CJ, NN);

    // Q pre-scaled by (1/16) * log2(e) so softmax runs in exp2 domain
    gemm_kernel<0, 320, 256><<<dim3(128, 4), 256, 0, stream>>>(
        Xu, wq, bq, Qb, nullptr, 0.0901684411f);
    gemm_kernel<0, 1024, 256><<<dim3(128, 4), 256, 0, stream>>>(
        Xj, wk, bk, Kb, nullptr, 1.0f);
    gemm_kernel<1, 1024, 320><<<dim3(128, 5), 256, 0, stream>>>(
        Xj, wv, bv, Vb, nullptr, 1.0f);

    attn_kernel<<<512, 384, 0, stream>>>(Qb, Kb, Vb, AO);

    gemm_kernel<2, 320, 320><<<dim3(128, 5), 256, 0, stream>>>(
        AO, wo, bo, out, unet, 1.0f);
}